// Round 1
// baseline (3354.996 us; speedup 1.0000x reference)
//
#include <hip/hip_runtime.h>
#include <hip/hip_bf16.h>
#include <cstdint>
#include <cstddef>

#define H_DIM 4096
#define BT_DIM 4096
#define V_DIM 32000
#define IGN (-100)

#define BM 128
#define BN 128
#define BK 64
#define NKSTEP (H_DIM / BK)   // 64
#define MTILES (BT_DIM / BM)  // 32
#define NTILES (V_DIM / BN)   // 250
#define NPAN (V_DIM / 64)     // 500 per-64-col panels

using f32x4  = __attribute__((ext_vector_type(4))) float;
using bf16x8 = __attribute__((ext_vector_type(8))) short;  // 8 bf16 in 4 VGPRs

__device__ __forceinline__ unsigned int packbf2(float a, float b) {
    union { __hip_bfloat16 h[2]; unsigned int u; } c;
    c.h[0] = __float2bfloat16(a);
    c.h[1] = __float2bfloat16(b);
    return c.u;
}

// GEMM (x @ W^T) fused with per-128-col-tile partial logsumexp + target-logit capture.
__global__ __launch_bounds__(256, 2)
void gemm_ce_kernel(const float* __restrict__ x, const int* __restrict__ target,
                    const float* __restrict__ W, float* __restrict__ pm,
                    float* __restrict__ ps, float* __restrict__ tl)
{
    __shared__ __align__(16) unsigned short sA[BM * BK];
    __shared__ __align__(16) unsigned short sB[BN * BK];

    const int bid = blockIdx.x;
    // bijective XCD swizzle: nwg = 8000 = 8 * 1000
    const int swz = (bid & 7) * 1000 + (bid >> 3);
    const int mt = swz & 31;   // M-tile fastest: same W panel co-resident per XCD
    const int nt = swz >> 5;   // 0..249

    const int t    = threadIdx.x;
    const int lane = t & 63;
    const int wid  = t >> 6;   // 4 waves
    const int wr   = wid >> 1; // wave row (0..1)
    const int wc   = wid & 1;  // wave col (0..1)

    // staging decomposition: u = float4 slot in row (k), rr = base row
    const int u  = t & 15;
    const int rr = t >> 4;

    const float* aBase = x + (size_t)(mt * BM + rr) * H_DIM + u * 4;
    const float* bBase = W + (size_t)(nt * BN + rr) * H_DIM + u * 4;

    // K-invariant LDS write offset: row = rr + p*16, so (row&7) == (rr&7)
    const int wOffBase = rr * 128 + ((u * 8) ^ ((rr & 7) << 4));
    unsigned char* sAb = (unsigned char*)sA;
    unsigned char* sBb = (unsigned char*)sB;

    // K-invariant LDS read offsets (XOR-swizzled)
    int aoff[2][4], boff[2][4];
#pragma unroll
    for (int s = 0; s < 2; ++s)
#pragma unroll
        for (int i = 0; i < 4; ++i) {
            int kb   = s * 64 + ((lane >> 4) << 4);       // k-bytes for this lane group
            int rowa = wr * 64 + i * 16 + (lane & 15);
            aoff[s][i] = rowa * 128 + (kb ^ ((rowa & 7) << 4));
            int rowb = wc * 64 + i * 16 + (lane & 15);
            boff[s][i] = rowb * 128 + (kb ^ ((rowb & 7) << 4));
        }

    f32x4 acc[4][4];
    const f32x4 zero4 = {0.0f, 0.0f, 0.0f, 0.0f};
#pragma unroll
    for (int i = 0; i < 4; ++i)
#pragma unroll
        for (int j = 0; j < 4; ++j) acc[i][j] = zero4;

    float4 ra[8], rb[8];
#pragma unroll
    for (int p = 0; p < 8; ++p) {           // prologue: tile 0
        ra[p] = *(const float4*)(aBase + (size_t)p * 16 * H_DIM);
        rb[p] = *(const float4*)(bBase + (size_t)p * 16 * H_DIM);
    }

    for (int kt = 0; kt < NKSTEP; ++kt) {
        // convert + LDS write of tile kt (swizzled)
#pragma unroll
        for (int p = 0; p < 8; ++p) {
            *(uint2*)(sAb + wOffBase + p * 2048) =
                make_uint2(packbf2(ra[p].x, ra[p].y), packbf2(ra[p].z, ra[p].w));
            *(uint2*)(sBb + wOffBase + p * 2048) =
                make_uint2(packbf2(rb[p].x, rb[p].y), packbf2(rb[p].z, rb[p].w));
        }
        __syncthreads();

        // prefetch tile kt+1 into registers; vmcnt lands at next iter's convert
        if (kt + 1 < NKSTEP) {
            const float* an = aBase + (size_t)(kt + 1) * BK;
            const float* bn = bBase + (size_t)(kt + 1) * BK;
#pragma unroll
            for (int p = 0; p < 8; ++p) {
                ra[p] = *(const float4*)(an + (size_t)p * 16 * H_DIM);
                rb[p] = *(const float4*)(bn + (size_t)p * 16 * H_DIM);
            }
        }

#pragma unroll
        for (int s = 0; s < 2; ++s) {
            bf16x8 af[4], bfr[4];
#pragma unroll
            for (int i = 0; i < 4; ++i) {
                af[i]  = *(const bf16x8*)(sAb + aoff[s][i]);
                bfr[i] = *(const bf16x8*)(sBb + boff[s][i]);
            }
#pragma unroll
            for (int mi = 0; mi < 4; ++mi)
#pragma unroll
                for (int ni = 0; ni < 4; ++ni)
                    acc[mi][ni] = __builtin_amdgcn_mfma_f32_16x16x32_bf16(
                        af[mi], bfr[ni], acc[mi][ni], 0, 0, 0);
        }
        __syncthreads();
    }

    // ---- fused CE epilogue ----
    // C/D layout: col = lane&15, row = (lane>>4)*4 + reg  (m89-verified)
    const int colbase = nt * BN + wc * 64;
#pragma unroll
    for (int mi = 0; mi < 4; ++mi) {
#pragma unroll
        for (int r = 0; r < 4; ++r) {
            int grow = mt * BM + wr * 64 + mi * 16 + ((lane >> 4) << 2) + r;
            // row max over this wave's 64 cols: 4 frags in-lane + 16 col-lanes
            float mx = fmaxf(fmaxf(acc[mi][0][r], acc[mi][1][r]),
                             fmaxf(acc[mi][2][r], acc[mi][3][r]));
#pragma unroll
            for (int d = 1; d < 16; d <<= 1) mx = fmaxf(mx, __shfl_xor(mx, d, 64));
            float sm = __expf(acc[mi][0][r] - mx) + __expf(acc[mi][1][r] - mx)
                     + __expf(acc[mi][2][r] - mx) + __expf(acc[mi][3][r] - mx);
#pragma unroll
            for (int d = 1; d < 16; d <<= 1) sm += __shfl_xor(sm, d, 64);
            if ((lane & 15) == 0) {
                int p = nt * 2 + wc;   // 64-col panel index
                pm[(size_t)grow * NPAN + p] = mx;
                ps[(size_t)grow * NPAN + p] = sm;
            }
            int tc = target[grow] - colbase;
            if (tc >= 0 && tc < 64 && (lane & 15) == (tc & 15)) {
                float v = (tc >> 4) == 0 ? acc[mi][0][r]
                        : (tc >> 4) == 1 ? acc[mi][1][r]
                        : (tc >> 4) == 2 ? acc[mi][2][r] : acc[mi][3][r];
                tl[grow] = v;
            }
        }
    }
}

// one wave per row: merge 500 (m,s) partials -> lse -> per-token loss -> atomic sum
__global__ __launch_bounds__(256)
void rowreduce_kernel(const int* __restrict__ target, const float* __restrict__ pm,
                      const float* __restrict__ ps, const float* __restrict__ tl,
                      float* __restrict__ sumcnt)
{
    const int row  = blockIdx.x * 4 + (threadIdx.x >> 6);
    const int lane = threadIdx.x & 63;
    float M = -INFINITY, S = 0.0f;
    for (int p = lane; p < NPAN; p += 64) {
        float m = pm[(size_t)row * NPAN + p];
        float s = ps[(size_t)row * NPAN + p];
        if (m > M) { S = S * __expf(M - m) + s; M = m; }
        else       { S += s * __expf(m - M); }
    }
#pragma unroll
    for (int d = 1; d < 64; d <<= 1) {
        float M2 = __shfl_xor(M, d, 64);
        float S2 = __shfl_xor(S, d, 64);
        float Mn = fmaxf(M, M2);
        S = S * __expf(M - Mn) + S2 * __expf(M2 - Mn);
        M = Mn;
    }
    if (lane == 0) {
        int t = target[row];
        if (t != IGN) {
            float per = M + logf(S) - tl[row];
            atomicAdd(&sumcnt[0], per);
            atomicAdd(&sumcnt[1], 1.0f);
        }
    }
}

__global__ void finalize_kernel(const float* __restrict__ sumcnt, float* __restrict__ out)
{
    out[0] = sumcnt[0] / fmaxf(sumcnt[1], 1.0f);
}

extern "C" void kernel_launch(void* const* d_in, const int* in_sizes, int n_in,
                              void* d_out, int out_size, void* d_ws, size_t ws_size,
                              hipStream_t stream) {
    const float* x      = (const float*)d_in[0];
    const int*   target = (const int*)d_in[1];
    const float* W      = (const float*)d_in[2];
    float* out = (float*)d_out;

    float* pm     = (float*)d_ws;                       // [BT][NPAN]
    float* ps     = pm + (size_t)BT_DIM * NPAN;         // [BT][NPAN]
    float* tl     = ps + (size_t)BT_DIM * NPAN;         // [BT]
    float* sumcnt = tl + BT_DIM;                        // [2]

    hipMemsetAsync(sumcnt, 0, 2 * sizeof(float), stream);
    gemm_ce_kernel<<<dim3(MTILES * NTILES), dim3(256), 0, stream>>>(x, target, W, pm, ps, tl);
    rowreduce_kernel<<<dim3(BT_DIM / 4), dim3(256), 0, stream>>>(target, pm, ps, tl, sumcnt);
    finalize_kernel<<<dim3(1), dim3(1), 0, stream>>>(sumcnt, out);
}